// Round 2
// baseline (112.896 us; speedup 1.0000x reference)
//
#include <hip/hip_runtime.h>

// Network constants (fixed by the reference)
#define BB 128
#define HH 8
#define RR 130
#define TT 256
#define NT 512   // threads per block (8 waves)

// ---------------------------------------------------------------------------
// Algebraic collapse (verified: first-launch validation passed in round 1):
//   gate = floor(sigmoid(z)) with |z| <= ~0.4  =>  gate == 0 exactly, all (b,h)
//   => rel*gate == 0 => A == 0 => GCN agg == 0 =>
//   feats = x + sum_i relu(gcn_b[i])  (broadcast over heads/rows)
//   fused = (sum_h fusion_w[h]) * feats + fusion_b
//   pooled[b,r] = Wsum * (mean_t x[b,r,:] + Sbar) + fb,  Sbar = mean_t S[t]
//   out = relu-MLP(pooled)
//
// Single fused kernel, one block per batch element. NO d_ws usage (round-1
// post-timing divergence was consistent with OOB scratch writes corrupting
// the harness's pristine-input copy).
// ---------------------------------------------------------------------------
__global__ __launch_bounds__(NT) void fused_net_kernel(
    const float* __restrict__ x,        // [B,R,T]
    const float* __restrict__ gcn_b,    // [8,256]
    const float* __restrict__ fusion_w, // [8]
    const float* __restrict__ fusion_b, // [1]
    const float* __restrict__ W1, const float* __restrict__ b1, // [64,130],[64]
    const float* __restrict__ W2, const float* __restrict__ b2, // [16,64],[16]
    const float* __restrict__ W3, const float* __restrict__ b3, // [5,16],[5]
    float* __restrict__ out) {          // [B,5]
    __shared__ float pooled[RR];
    __shared__ float red[NT];
    __shared__ float h1s[64];
    __shared__ float h2s[16];
    __shared__ float sWsum, sSbar;

    const int b    = blockIdx.x;
    const int t    = threadIdx.x;
    const int wave = t >> 6;            // 0..7
    const int lane = t & 63;

    // ---- per-row mean of x[b] : wave-per-row, one float4 per lane ----
    const float4* xb = reinterpret_cast<const float4*>(x + (size_t)b * RR * TT);
    for (int r = wave; r < RR; r += NT / 64) {
        float4 v = xb[r * 64 + lane];
        float s = (v.x + v.y) + (v.z + v.w);
#pragma unroll
        for (int off = 32; off > 0; off >>= 1)
            s += __shfl_down(s, off, 64);
        if (lane == 0) pooled[r] = s * (1.0f / TT);
    }

    // ---- Sbar = mean_t sum_i relu(gcn_b[i][t]) : block reduce over 2048 ----
    float sgb = 0.f;
    for (int j = t; j < HH * TT; j += NT) sgb += fmaxf(gcn_b[j], 0.f);
    red[t] = sgb;
    __syncthreads();                    // also makes pooled[] writes visible
    for (int off = NT / 2; off > 0; off >>= 1) {
        if (t < off) red[t] += red[t + off];
        __syncthreads();
    }
    if (t == 0) {
        float w = 0.f;
#pragma unroll
        for (int h = 0; h < HH; ++h) w += fusion_w[h];
        sWsum = w;
        sSbar = red[0] * (1.0f / TT);
    }
    __syncthreads();

    // ---- pooled[r] = Wsum*(xbar + Sbar) + fb ----
    const float Wsum = sWsum, Sbar = sSbar, fb = fusion_b[0];
    if (t < RR) pooled[t] = Wsum * (pooled[t] + Sbar) + fb;
    __syncthreads();

    // ---- MLP head: 130 -> 64 -> 16 -> 5, relu each layer ----
    if (t < 64) {
        float a = b1[t];
        for (int r = 0; r < RR; ++r) a = fmaf(W1[t * RR + r], pooled[r], a);
        h1s[t] = fmaxf(a, 0.f);
    }
    __syncthreads();

    if (t < 16) {
        float a = b2[t];
#pragma unroll
        for (int j = 0; j < 64; ++j) a = fmaf(W2[t * 64 + j], h1s[j], a);
        h2s[t] = fmaxf(a, 0.f);
    }
    __syncthreads();

    if (t < 5) {
        float a = b3[t];
#pragma unroll
        for (int j = 0; j < 16; ++j) a = fmaf(W3[t * 16 + j], h2s[j], a);
        out[b * 5 + t] = fmaxf(a, 0.f);
    }
}

// ---------------------------------------------------------------------------
// Input order (setup_inputs dict order):
//  0 x [128,130,256]
//  1 Wq  2 bq  3 Wk  4 bk  5 threshold      (dead: gate==0 kills rel exactly)
//  6 se_W1 7 se_b1 8 se_W2 9 se_b2          (dead: floor(sigmoid(|z|<0.5))==0)
// 10 gcn_W [8,256,256] (dead)  11 gcn_b [8,256]
// 12 fusion_w [8]  13 fusion_b [1]
// 14 mlp_W1 [64,130] 15 mlp_b1 [64]
// 16 mlp_W2 [16,64]  17 mlp_b2 [16]
// 18 mlp_W3 [5,16]   19 mlp_b3 [5]
// ---------------------------------------------------------------------------
extern "C" void kernel_launch(void* const* d_in, const int* in_sizes, int n_in,
                              void* d_out, int out_size, void* d_ws, size_t ws_size,
                              hipStream_t stream) {
    const float* x        = (const float*)d_in[0];
    const float* gcn_b    = (const float*)d_in[11];
    const float* fusion_w = (const float*)d_in[12];
    const float* fusion_b = (const float*)d_in[13];
    const float* W1 = (const float*)d_in[14];
    const float* b1 = (const float*)d_in[15];
    const float* W2 = (const float*)d_in[16];
    const float* b2 = (const float*)d_in[17];
    const float* W3 = (const float*)d_in[18];
    const float* b3 = (const float*)d_in[19];

    float* outf = (float*)d_out;             // [128,5] float32

    fused_net_kernel<<<BB, NT, 0, stream>>>(x, gcn_b, fusion_w, fusion_b,
                                            W1, b1, W2, b2, W3, b3, outf);
}